// Round 1
// baseline (514.853 us; speedup 1.0000x reference)
//
#include <hip/hip_runtime.h>

#define NBATCH 16
#define NCH 64
#define CPG 4
#define NGRP 16
#define EPSV 1e-5f

// ws layout (bytes):
//   0     : S1  [16][64] float  (4096)
//   4096  : S2  [16][64] float  (4096)
//   8192  : cnt [16] int        (64)   -- zeroed region ends at 8256
//   8448  : A   [16][64] float  (4096)
//   12544 : B   [16][64] float  (4096)

__global__ void ogn_stats(const float* __restrict__ data,
                          const int* __restrict__ bid,
                          float* __restrict__ S1,
                          float* __restrict__ S2,
                          int* __restrict__ cnt,
                          int N, int rows_per_block) {
    __shared__ float ls1[NBATCH * NCH];
    __shared__ float ls2[NBATCH * NCH];
    __shared__ int   lcnt[NBATCH];

    for (int i = threadIdx.x; i < NBATCH * NCH; i += blockDim.x) {
        ls1[i] = 0.f;
        ls2[i] = 0.f;
    }
    if (threadIdx.x < NBATCH) lcnt[threadIdx.x] = 0;
    __syncthreads();

    const int t     = threadIdx.x;
    const int c4    = t & 15;   // which float4 of the 64-ch row
    const int rlane = t >> 4;   // 0..15: row within a 16-row sweep

    long long row_begin = (long long)blockIdx.x * rows_per_block;
    long long row_end   = row_begin + rows_per_block;
    if (row_end > N) row_end = N;

    const float4* data4 = (const float4*)data;

    float4 s1 = make_float4(0.f, 0.f, 0.f, 0.f);
    float4 s2 = make_float4(0.f, 0.f, 0.f, 0.f);
    int cur = -1;
    int c   = 0;

    for (long long r = row_begin + rlane; r < row_end; r += 16) {
        int b = bid[r];
        if (b != cur) {
            if (cur >= 0) {
                int base = cur * NCH + c4 * 4;
                atomicAdd(&ls1[base + 0], s1.x);
                atomicAdd(&ls1[base + 1], s1.y);
                atomicAdd(&ls1[base + 2], s1.z);
                atomicAdd(&ls1[base + 3], s1.w);
                atomicAdd(&ls2[base + 0], s2.x);
                atomicAdd(&ls2[base + 1], s2.y);
                atomicAdd(&ls2[base + 2], s2.z);
                atomicAdd(&ls2[base + 3], s2.w);
                if (c4 == 0) atomicAdd(&lcnt[cur], c);
            }
            s1 = make_float4(0.f, 0.f, 0.f, 0.f);
            s2 = make_float4(0.f, 0.f, 0.f, 0.f);
            c = 0;
            cur = b;
        }
        float4 v = data4[r * 16 + c4];
        s1.x += v.x; s1.y += v.y; s1.z += v.z; s1.w += v.w;
        s2.x += v.x * v.x; s2.y += v.y * v.y; s2.z += v.z * v.z; s2.w += v.w * v.w;
        c++;
    }
    if (cur >= 0) {
        int base = cur * NCH + c4 * 4;
        atomicAdd(&ls1[base + 0], s1.x);
        atomicAdd(&ls1[base + 1], s1.y);
        atomicAdd(&ls1[base + 2], s1.z);
        atomicAdd(&ls1[base + 3], s1.w);
        atomicAdd(&ls2[base + 0], s2.x);
        atomicAdd(&ls2[base + 1], s2.y);
        atomicAdd(&ls2[base + 2], s2.z);
        atomicAdd(&ls2[base + 3], s2.w);
        if (c4 == 0) atomicAdd(&lcnt[cur], c);
    }
    __syncthreads();

    for (int i = threadIdx.x; i < NBATCH * NCH; i += blockDim.x) {
        float v1 = ls1[i];
        float v2 = ls2[i];
        if (v1 != 0.f) atomicAdd(&S1[i], v1);
        if (v2 != 0.f) atomicAdd(&S2[i], v2);
    }
    if (threadIdx.x < NBATCH) {
        int v = lcnt[threadIdx.x];
        if (v != 0) atomicAdd(&cnt[threadIdx.x], v);
    }
}

__global__ void ogn_params(const float* __restrict__ S1,
                           const float* __restrict__ S2,
                           const int* __restrict__ cnt,
                           const float* __restrict__ w,
                           const float* __restrict__ bias,
                           float* __restrict__ A,
                           float* __restrict__ B) {
    int t = threadIdx.x;           // 256 threads: (batch, group)
    if (t >= NBATCH * NGRP) return;
    int b = t >> 4;
    int g = t & 15;

    int base = b * NCH + g * CPG;
    float s1g = 0.f, s2g = 0.f;
#pragma unroll
    for (int k = 0; k < CPG; ++k) {
        s1g += S1[base + k];
        s2g += S2[base + k];
    }
    float countf    = (float)cnt[b] * (float)CPG;
    float inv_count = 1.f / (countf + EPSV);
    float mean      = s1g * inv_count;
    float var       = inv_count * (s2g - 2.f * mean * s1g + countf * mean * mean);
    float inv_std   = rsqrtf(var + EPSV);

#pragma unroll
    for (int k = 0; k < CPG; ++k) {
        int ch = g * CPG + k;
        float wv = w[ch];
        float bv = bias[ch];
        A[b * NCH + ch] = inv_std * wv;
        B[b * NCH + ch] = bv - mean * inv_std * wv;
    }
}

__global__ void ogn_apply(const float* __restrict__ data,
                          const int* __restrict__ bid,
                          const float* __restrict__ A,
                          const float* __restrict__ B,
                          float* __restrict__ out,
                          long long total4) {
    const float4* d4 = (const float4*)data;
    const float4* A4 = (const float4*)A;
    const float4* B4 = (const float4*)B;
    float4* o4 = (float4*)out;

    long long i      = (long long)blockIdx.x * blockDim.x + threadIdx.x;
    long long stride = (long long)gridDim.x * blockDim.x;

    for (; i < total4; i += stride) {
        long long row = i >> 4;
        int c4 = (int)(i & 15);
        int b  = bid[row];
        float4 v  = d4[i];
        float4 a  = A4[b * 16 + c4];
        float4 bb = B4[b * 16 + c4];
        float4 r;
        r.x = fmaf(v.x, a.x, bb.x);
        r.y = fmaf(v.y, a.y, bb.y);
        r.z = fmaf(v.z, a.z, bb.z);
        r.w = fmaf(v.w, a.w, bb.w);
        o4[i] = r;
    }
}

extern "C" void kernel_launch(void* const* d_in, const int* in_sizes, int n_in,
                              void* d_out, int out_size, void* d_ws, size_t ws_size,
                              hipStream_t stream) {
    const float* data = (const float*)d_in[0];
    const int*   bid  = (const int*)d_in[1];
    const float* w    = (const float*)d_in[2];
    const float* bias = (const float*)d_in[3];
    float* out = (float*)d_out;

    int N = in_sizes[1];  // batch_id count

    char* ws = (char*)d_ws;
    float* S1  = (float*)(ws + 0);
    float* S2  = (float*)(ws + 4096);
    int*   cnt = (int*)  (ws + 8192);
    float* A   = (float*)(ws + 8448);
    float* B   = (float*)(ws + 12544);

    // zero the accumulator region (S1, S2, cnt)
    hipMemsetAsync(d_ws, 0, 8256, stream);

    const int NB1 = 1024;
    int rows_per_block = (N + NB1 - 1) / NB1;
    ogn_stats<<<NB1, 256, 0, stream>>>(data, bid, S1, S2, cnt, N, rows_per_block);

    ogn_params<<<1, 256, 0, stream>>>(S1, S2, cnt, w, bias, A, B);

    long long total4 = (long long)N * (NCH / 4);
    int NB3 = 8192;
    ogn_apply<<<NB3, 256, 0, stream>>>(data, bid, A, B, out, total4);
}